// Round 1
// baseline (817.691 us; speedup 1.0000x reference)
//
#include <hip/hip_runtime.h>
#include <hip/hip_bf16.h>
#include <stdint.h>

#define GCN_N 50000
#define GCN_E 800000
#define GCN_D 256

// ---------------- preprocessing kernels ----------------

__global__ void init_kernel(float* deg, int* counts, int* cursor, int n) {
    int i = blockIdx.x * blockDim.x + threadIdx.x;
    if (i < n) { deg[i] = 1.0f; counts[i] = 0; cursor[i] = 0; }
}

__global__ void edge_mlp_kernel(const float* __restrict__ attr,
                                const int* __restrict__ dst,
                                const float* __restrict__ mw1, const float* __restrict__ mb1,
                                const float* __restrict__ mw2, const float* __restrict__ mb2,
                                float* __restrict__ ew, float* __restrict__ deg,
                                int* __restrict__ counts, int e_count) {
    int e = blockIdx.x * blockDim.x + threadIdx.x;
    if (e >= e_count) return;
    float a = attr[e];
    float s = mb2[0];
#pragma unroll
    for (int j = 0; j < 8; ++j) {
        float hj = fmaf(a, mw1[j], mb1[j]);
        hj = fmaxf(hj, 0.0f);
        s = fmaf(hj, mw2[j], s);
    }
    float w = 1.0f / (1.0f + expf(-s));
    ew[e] = w;
    int d = dst[e];
    atomicAdd(&deg[d], w);
    atomicAdd(&counts[d], 1);
}

__global__ void node_kernel(const float* __restrict__ deg, float* __restrict__ dinv,
                            float* __restrict__ invdeg, int n) {
    int i = blockIdx.x * blockDim.x + threadIdx.x;
    if (i < n) {
        float d = deg[i];
        dinv[i] = rsqrtf(d);
        invdeg[i] = 1.0f / d;
    }
}

__global__ __launch_bounds__(1024) void scan1_kernel(const int* __restrict__ counts,
                                                     int* __restrict__ part,
                                                     int* __restrict__ bsum, int n) {
    __shared__ int s[1024];
    int tid = threadIdx.x;
    int i = blockIdx.x * 1024 + tid;
    int v = (i < n) ? counts[i] : 0;
    s[tid] = v;
    __syncthreads();
#pragma unroll
    for (int d = 1; d < 1024; d <<= 1) {
        int t = (tid >= d) ? s[tid - d] : 0;
        __syncthreads();
        s[tid] += t;
        __syncthreads();
    }
    if (i < n) part[i] = s[tid] - v;  // exclusive within block
    if (tid == 1023) bsum[blockIdx.x] = s[1023];
}

__global__ void scan2_kernel(int* bsum, int nb) {
    if (threadIdx.x == 0 && blockIdx.x == 0) {
        int run = 0;
        for (int b = 0; b < nb; ++b) { int t = bsum[b]; bsum[b] = run; run += t; }
    }
}

__global__ void scan3_kernel(const int* __restrict__ part, const int* __restrict__ bsum,
                             int* __restrict__ offs, int n, int e_total) {
    int i = blockIdx.x * blockDim.x + threadIdx.x;
    if (i < n) offs[i] = part[i] + bsum[i >> 10];
    if (i == 0) offs[n] = e_total;
}

__global__ void scatter_kernel(const int* __restrict__ src, const int* __restrict__ dst,
                               const float* __restrict__ ew, const float* __restrict__ dinv,
                               const int* __restrict__ offs, int* __restrict__ cursor,
                               int* __restrict__ csr_src, float* __restrict__ csr_w,
                               int e_count) {
    int e = blockIdx.x * blockDim.x + threadIdx.x;
    if (e >= e_count) return;
    int sN = src[e], dN = dst[e];
    int pos = offs[dN] + atomicAdd(&cursor[dN], 1);
    csr_src[pos] = sN;
    csr_w[pos] = dinv[sN] * ew[e] * dinv[dN];
}

// ---------------- GEMM: h = x @ W + b  (fp32, vector ALU) ----------------
// block: 256 threads = 4 waves; tile: 64 rows x 256 cols.
// wave w computes rows r0=16w..16w+15, all 256 cols (lane c covers c+64j).
// x tile staged in LDS k-major so fragment reads are wave-uniform broadcasts.

__global__ __launch_bounds__(256) void gemm_kernel(const float* __restrict__ x,
                                                   const float* __restrict__ W,
                                                   const float* __restrict__ b,
                                                   float* __restrict__ out, int n_rows) {
    __shared__ float xs[16][64];
    const int tid = threadIdx.x;
    const int c = tid & 63;
    const int r0 = (tid >> 6) * 16;
    const int row0 = blockIdx.x * 64;
    const int lr = tid & 63;          // row this thread loads
    const int kk4 = (tid >> 6) * 4;   // k offset this thread loads

    float acc[16][4];
#pragma unroll
    for (int r = 0; r < 16; ++r) {
        acc[r][0] = 0.f; acc[r][1] = 0.f; acc[r][2] = 0.f; acc[r][3] = 0.f;
    }

    for (int k0 = 0; k0 < GCN_D; k0 += 16) {
        __syncthreads();
        {
            int gr = row0 + lr;
            float4 xv = make_float4(0.f, 0.f, 0.f, 0.f);
            if (gr < n_rows) xv = *(const float4*)&x[gr * GCN_D + k0 + kk4];
            xs[kk4 + 0][lr] = xv.x;
            xs[kk4 + 1][lr] = xv.y;
            xs[kk4 + 2][lr] = xv.z;
            xs[kk4 + 3][lr] = xv.w;
        }
        __syncthreads();
#pragma unroll
        for (int kk = 0; kk < 16; ++kk) {
            float4 xa = *(const float4*)&xs[kk][r0];
            float4 xb = *(const float4*)&xs[kk][r0 + 4];
            float4 xc = *(const float4*)&xs[kk][r0 + 8];
            float4 xd = *(const float4*)&xs[kk][r0 + 12];
            const float* Wr = &W[(k0 + kk) * GCN_D + c];
            float w0 = Wr[0], w1 = Wr[64], w2 = Wr[128], w3 = Wr[192];
            float xv_[16] = {xa.x, xa.y, xa.z, xa.w, xb.x, xb.y, xb.z, xb.w,
                             xc.x, xc.y, xc.z, xc.w, xd.x, xd.y, xd.z, xd.w};
#pragma unroll
            for (int r = 0; r < 16; ++r) {
                acc[r][0] = fmaf(xv_[r], w0, acc[r][0]);
                acc[r][1] = fmaf(xv_[r], w1, acc[r][1]);
                acc[r][2] = fmaf(xv_[r], w2, acc[r][2]);
                acc[r][3] = fmaf(xv_[r], w3, acc[r][3]);
            }
        }
    }
    float b0 = b[c], b1 = b[c + 64], b2 = b[c + 128], b3 = b[c + 192];
#pragma unroll
    for (int r = 0; r < 16; ++r) {
        int gr = row0 + r0 + r;
        if (gr < n_rows) {
            float* o = &out[gr * GCN_D + c];
            o[0]   = acc[r][0] + b0;
            o[64]  = acc[r][1] + b1;
            o[128] = acc[r][2] + b2;
            o[192] = acc[r][3] + b3;
        }
    }
}

// ---------------- SpMM: out = A_norm*h + diag(1/deg)*h, optional relu ----------------
// one wave per node; lane handles 4 contiguous cols (float4).

__global__ __launch_bounds__(256) void spmm_kernel(const float* __restrict__ h,
                                                   const int* __restrict__ offs,
                                                   const int* __restrict__ csr_src,
                                                   const float* __restrict__ csr_w,
                                                   const float* __restrict__ invdeg,
                                                   float* __restrict__ out, int n, int relu) {
    int wid = (blockIdx.x * blockDim.x + threadIdx.x) >> 6;
    int lane = threadIdx.x & 63;
    if (wid >= n) return;
    const float4* h4 = (const float4*)h;
    float4 acc = h4[wid * 64 + lane];
    float sw = invdeg[wid];
    acc.x *= sw; acc.y *= sw; acc.z *= sw; acc.w *= sw;
    int e0 = offs[wid], e1 = offs[wid + 1];
    for (int k = e0; k < e1; ++k) {
        int s = csr_src[k];
        float w = csr_w[k];
        float4 hv = h4[s * 64 + lane];
        acc.x = fmaf(w, hv.x, acc.x);
        acc.y = fmaf(w, hv.y, acc.y);
        acc.z = fmaf(w, hv.z, acc.z);
        acc.w = fmaf(w, hv.w, acc.w);
    }
    if (relu) {
        acc.x = fmaxf(acc.x, 0.f);
        acc.y = fmaxf(acc.y, 0.f);
        acc.z = fmaxf(acc.z, 0.f);
        acc.w = fmaxf(acc.w, 0.f);
    }
    ((float4*)out)[wid * 64 + lane] = acc;
}

// ---------------- launch ----------------

extern "C" void kernel_launch(void* const* d_in, const int* in_sizes, int n_in,
                              void* d_out, int out_size, void* d_ws, size_t ws_size,
                              hipStream_t stream) {
    const float* x    = (const float*)d_in[0];
    const int*   ei   = (const int*)d_in[1];
    const float* attr = (const float*)d_in[2];
    const float* W1 = (const float*)d_in[3];  const float* b1 = (const float*)d_in[4];
    const float* W2 = (const float*)d_in[5];  const float* b2 = (const float*)d_in[6];
    const float* W3 = (const float*)d_in[7];  const float* b3 = (const float*)d_in[8];
    const float* mw1 = (const float*)d_in[9]; const float* mb1 = (const float*)d_in[10];
    const float* mw2 = (const float*)d_in[11];const float* mb2 = (const float*)d_in[12];
    float* out = (float*)d_out;

    const int N = GCN_N, E = GCN_E;
    const int* srcI = ei;
    const int* dstI = ei + E;

    float* ws = (float*)d_ws;
    float* ew     = ws;            // E
    float* deg    = ew + E;        // N
    float* dinv   = deg + N;       // N
    float* invdeg = dinv + N;      // N
    int* counts  = (int*)(invdeg + N);  // N
    int* cursor  = counts + N;          // N
    int* offs    = cursor + N;          // N+1
    int* bsum    = offs + N + 1;        // 64
    int* part    = bsum + 64;           // N
    int* csr_src = part + N;            // E
    float* csr_w = (float*)(csr_src + E);  // E
    float* h = (float*)(((uintptr_t)(csr_w + E) + 255) & ~(uintptr_t)255);  // N*256

    init_kernel<<<(N + 255) / 256, 256, 0, stream>>>(deg, counts, cursor, N);
    edge_mlp_kernel<<<(E + 255) / 256, 256, 0, stream>>>(attr, dstI, mw1, mb1, mw2, mb2,
                                                         ew, deg, counts, E);
    node_kernel<<<(N + 255) / 256, 256, 0, stream>>>(deg, dinv, invdeg, N);
    int nb = (N + 1023) / 1024;
    scan1_kernel<<<nb, 1024, 0, stream>>>(counts, part, bsum, N);
    scan2_kernel<<<1, 64, 0, stream>>>(bsum, nb);
    scan3_kernel<<<(N + 255) / 256, 256, 0, stream>>>(part, bsum, offs, N, E);
    scatter_kernel<<<(E + 255) / 256, 256, 0, stream>>>(srcI, dstI, ew, dinv, offs, cursor,
                                                        csr_src, csr_w, E);

    const int gemm_grid = (N + 63) / 64;
    const int spmm_grid = (N * 64 + 255) / 256;

    // layer 1
    gemm_kernel<<<gemm_grid, 256, 0, stream>>>(x, W1, b1, h, N);
    spmm_kernel<<<spmm_grid, 256, 0, stream>>>(h, offs, csr_src, csr_w, invdeg, out, N, 1);
    // layer 2
    gemm_kernel<<<gemm_grid, 256, 0, stream>>>(out, W2, b2, h, N);
    spmm_kernel<<<spmm_grid, 256, 0, stream>>>(h, offs, csr_src, csr_w, invdeg, out, N, 1);
    // layer 3
    gemm_kernel<<<gemm_grid, 256, 0, stream>>>(out, W3, b3, h, N);
    spmm_kernel<<<spmm_grid, 256, 0, stream>>>(h, offs, csr_src, csr_w, invdeg, out, N, 0);
}